// Round 1
// baseline (807.084 us; speedup 1.0000x reference)
//
#include <hip/hip_runtime.h>
#include <cstdint>
#include <cstddef>

#define DEV __device__ __forceinline__

typedef unsigned short u16;
typedef __attribute__((ext_vector_type(8))) short bf16x8;   // 8 bf16 (4 VGPRs), per guide
typedef __attribute__((ext_vector_type(8))) u16  u16x8;
typedef __attribute__((ext_vector_type(4))) float f32x4;

constexpr int Bn = 4, Sn = 2048, Dn = 1024, Hn = 16, Fn = 4096, DKn = 64;
constexpr int Mn = Bn * Sn;   // 8192 rows

// ---------- bf16 helpers (bit-level, RNE) ----------
DEV u16 f2b(float f) {
    unsigned u = __float_as_uint(f);
    unsigned r = (u + 0x7fffu + ((u >> 16) & 1u)) >> 16;
    return (u16)r;
}
DEV float b2f(u16 h) { return __uint_as_float(((unsigned)h) << 16); }

// ---------- async global->LDS (16B/lane, LDS dest = wave-uniform base + lane*16) ----------
typedef __attribute__((address_space(1))) void gvoid;
typedef __attribute__((address_space(3))) void lvoid;
DEV void gl_lds16(const u16* g, u16* l) {
    __builtin_amdgcn_global_load_lds((gvoid*)g, (lvoid*)l, 16, 0, 0);
}

DEV f32x4 mfma16(bf16x8 a, bf16x8 b, f32x4 c) {
    return __builtin_amdgcn_mfma_f32_16x16x32_bf16(a, b, c, 0, 0, 0);
}

// ---------- f32 -> bf16 elementwise ----------
__global__ __launch_bounds__(256) void cvt_f32_bf16(const float* __restrict__ in,
                                                    u16* __restrict__ out) {
    size_t i = ((size_t)blockIdx.x * 256 + threadIdx.x) * 8;
    float4 a = *(const float4*)(in + i);
    float4 b = *(const float4*)(in + i + 4);
    u16x8 o;
    o[0] = f2b(a.x); o[1] = f2b(a.y); o[2] = f2b(a.z); o[3] = f2b(a.w);
    o[4] = f2b(b.x); o[5] = f2b(b.y); o[6] = f2b(b.z); o[7] = f2b(b.w);
    *(u16x8*)(out + i) = o;
}

// ---------- W (K x N f32) -> Wt (N x K bf16) ----------
__global__ __launch_bounds__(256) void transpose_cvt(const float* __restrict__ W,
                                                     u16* __restrict__ Wt, int K, int N) {
    __shared__ float tile[32][33];
    int n0 = blockIdx.x * 32, k0 = blockIdx.y * 32;
    int tx = threadIdx.x, ty = threadIdx.y;   // (32,8)
    for (int r = ty; r < 32; r += 8) tile[r][tx] = W[(size_t)(k0 + r) * N + n0 + tx];
    __syncthreads();
    for (int r = ty; r < 32; r += 8) Wt[(size_t)(n0 + r) * K + k0 + tx] = f2b(tile[tx][r]);
}

// ---------- GEMM: C[M,N] = A[M,K] * Bt[N,K]^T + bias, fused epilogues ----------
// RELU: relu epilogue. RESID: 0 none, 1 f32 residual, 2 bf16 residual.
// OUT_BF16: bf16 output. QKV: remap (b*S+s, h*64+dk) -> (b*H+h, s, dk) bf16 output.
template <int RELU, int RESID, int OUT_BF16, int QKV>
__global__ __launch_bounds__(256) void gemm_kernel(
    const u16* __restrict__ A, const u16* __restrict__ Bt,
    const float* __restrict__ bias,
    const float* __restrict__ residF, const u16* __restrict__ residB,
    float* __restrict__ Cf, u16* __restrict__ Cb,
    int M, int N, int K) {
    constexpr int BK = 32;
    __shared__ __align__(16) u16 As[128 * BK];   // 8 KB, row-major [128][32]
    __shared__ __align__(16) u16 Bs[128 * BK];   // 8 KB
    const int tid = threadIdx.x, wave = tid >> 6, lane = tid & 63;
    const int quad = lane >> 4, l16 = lane & 15;
    const int row0 = blockIdx.x * 128, col0 = blockIdx.y * 128;
    const int wm = wave & 1, wn = wave >> 1;     // 2x2 wave grid, 64x64 per wave

    f32x4 acc[4][4];
    for (int mt = 0; mt < 4; mt++)
        for (int nt = 0; nt < 4; nt++)
            acc[mt][nt] = f32x4{0.f, 0.f, 0.f, 0.f};

    // staging: per wave, per pass p: rows p*64 + wave*16 + lane/4, col (lane&3)*8
    const int srow = lane >> 2, scol = (lane & 3) * 8;
    const u16* Ag = A + (size_t)(row0 + wave * 16 + srow) * K + scol;
    const u16* Bg = Bt + (size_t)(col0 + wave * 16 + srow) * K + scol;
    u16* AsW = As + (wave * 16) * BK;
    u16* BsW = Bs + (wave * 16) * BK;

    for (int k0 = 0; k0 < K; k0 += BK) {
        __syncthreads();   // protect LDS from overwrite while prior reads in flight
        gl_lds16(Ag + k0, AsW);
        gl_lds16(Ag + (size_t)64 * K + k0, AsW + 64 * BK);
        gl_lds16(Bg + k0, BsW);
        gl_lds16(Bg + (size_t)64 * K + k0, BsW + 64 * BK);
        __syncthreads();   // compiler emits s_waitcnt vmcnt(0) before s_barrier

        bf16x8 af[4], bfr[4];
        for (int mt = 0; mt < 4; mt++)
            af[mt] = *(const bf16x8*)(As + (wm * 64 + mt * 16 + l16) * BK + quad * 8);
        for (int nt = 0; nt < 4; nt++)
            bfr[nt] = *(const bf16x8*)(Bs + (wn * 64 + nt * 16 + l16) * BK + quad * 8);
        for (int mt = 0; mt < 4; mt++)
            for (int nt = 0; nt < 4; nt++)
                acc[mt][nt] = mfma16(af[mt], bfr[nt], acc[mt][nt]);
    }

    // epilogue. C layout: col = lane&15, row = quad*4 + reg (verified m89/m91)
    for (int nt = 0; nt < 4; nt++) {
        int col = col0 + wn * 64 + nt * 16 + l16;
        float bv = bias[col];
        for (int mt = 0; mt < 4; mt++) {
            int rbase = row0 + wm * 64 + mt * 16 + quad * 4;
            for (int r = 0; r < 4; r++) {
                int row = rbase + r;
                float v = acc[mt][nt][r] + bv;
                if (RELU) v = fmaxf(v, 0.f);
                if (RESID == 1) v += residF[(size_t)row * N + col];
                if (RESID == 2) v += b2f(residB[(size_t)row * N + col]);
                if (QKV) {
                    int bb = row >> 11, s = row & 2047, h = col >> 6, dk = col & 63;
                    Cb[((size_t)(bb * Hn + h) * Sn + s) * DKn + dk] = f2b(v);
                } else if (OUT_BF16) {
                    Cb[(size_t)row * N + col] = f2b(v);
                } else {
                    Cf[(size_t)row * N + col] = v;
                }
            }
        }
    }
}

// ---------- causal flash attention ----------
// Q,K,V: (B*H, S, DK) bf16. O: (B, S, H*DK) bf16.
// Block: 64 Q rows (4 waves x 16 rows), loop over 64-row K/V tiles (causal).
__global__ __launch_bounds__(256) void attn_kernel(const u16* __restrict__ Q,
                                                   const u16* __restrict__ K,
                                                   const u16* __restrict__ V,
                                                   u16* __restrict__ O) {
    constexpr int STR = 72;   // padded LDS row stride (16B-aligned, breaks 16-way conflicts)
    __shared__ __align__(16) u16 Ks[64 * STR];        // [s][d]
    __shared__ __align__(16) u16 Vts[64 * STR];       // [d][s] (transposed)
    __shared__ __align__(16) u16 Ps[4 * 16 * STR];    // per-wave P strips
    int qt = blockIdx.x, bh = blockIdx.y;
    int b = bh >> 4, h = bh & 15;
    const u16* Qh = Q + (size_t)bh * Sn * DKn;
    const u16* Kh = K + (size_t)bh * Sn * DKn;
    const u16* Vh = V + (size_t)bh * Sn * DKn;
    int tid = threadIdx.x, wave = tid >> 6, lane = tid & 63;
    int quad = lane >> 4, l16 = lane & 15;

    // Q fragments held in registers for whole block (A layout: m=l16, k=quad*8+j)
    int qrow = qt * 64 + wave * 16 + l16;
    bf16x8 qf0 = *(const bf16x8*)(Qh + (size_t)qrow * DKn + quad * 8);
    bf16x8 qf1 = *(const bf16x8*)(Qh + (size_t)qrow * DKn + 32 + quad * 8);

    float m_i[4], l_i[4];
    f32x4 acc_o[4];
    for (int r = 0; r < 4; r++) { m_i[r] = -1e30f; l_i[r] = 0.f; }
    for (int nt = 0; nt < 4; nt++) acc_o[nt] = f32x4{0.f, 0.f, 0.f, 0.f};

    u16* Pw = Ps + wave * 16 * STR;
    int rowg0 = qt * 64 + wave * 16 + quad * 4;

    for (int kt = 0; kt <= qt; kt++) {
        const u16* Kg = Kh + (size_t)kt * 64 * DKn;
        const u16* Vg = Vh + (size_t)kt * 64 * DKn;
        for (int c = 0; c < 2; c++) {
            int idx = (c * 256 + tid) * 8;
            int s = idx >> 6, d = idx & 63;
            *(bf16x8*)(Ks + s * STR + d) = *(const bf16x8*)(Kg + idx);
            bf16x8 vv = *(const bf16x8*)(Vg + idx);
            for (int j = 0; j < 8; j++) Vts[(d + j) * STR + s] = (u16)vv[j];
        }
        __syncthreads();

        // Sc = Q K^T (wave strip 16 x 64)
        f32x4 sc[4];
        for (int nt = 0; nt < 4; nt++) sc[nt] = f32x4{0.f, 0.f, 0.f, 0.f};
        for (int nt = 0; nt < 4; nt++) {
            bf16x8 kf0 = *(const bf16x8*)(Ks + (nt * 16 + l16) * STR + quad * 8);
            bf16x8 kf1 = *(const bf16x8*)(Ks + (nt * 16 + l16) * STR + 32 + quad * 8);
            sc[nt] = mfma16(qf0, kf0, sc[nt]);
            sc[nt] = mfma16(qf1, kf1, sc[nt]);
        }
        bool diag = (kt == qt);
        // online softmax; row = quad*4 + r, col = nt*16 + l16 (C layout)
        for (int r = 0; r < 4; r++) {
            float mx = -1e30f;
            for (int nt = 0; nt < 4; nt++) {
                float v = sc[nt][r] * 0.125f;   // 1/sqrt(64)
                if (diag && (kt * 64 + nt * 16 + l16 > rowg0 + r)) v = -1e30f;
                sc[nt][r] = v;
                mx = fmaxf(mx, v);
            }
            for (int off = 1; off < 16; off <<= 1) mx = fmaxf(mx, __shfl_xor(mx, off, 64));
            float mnew = fmaxf(m_i[r], mx);
            float alpha = __expf(m_i[r] - mnew);
            m_i[r] = mnew;
            float su = 0.f;
            for (int nt = 0; nt < 4; nt++) {
                float p = __expf(sc[nt][r] - mnew);
                sc[nt][r] = p;
                su += p;
            }
            for (int off = 1; off < 16; off <<= 1) su += __shfl_xor(su, off, 64);
            l_i[r] = l_i[r] * alpha + su;
            for (int nt = 0; nt < 4; nt++) acc_o[nt][r] *= alpha;
        }
        // P: C layout -> LDS -> A layout (wave-private strip, no barrier needed)
        for (int r = 0; r < 4; r++)
            for (int nt = 0; nt < 4; nt++)
                Pw[(quad * 4 + r) * STR + nt * 16 + l16] = f2b(sc[nt][r]);
        bf16x8 pf0 = *(const bf16x8*)(Pw + l16 * STR + quad * 8);
        bf16x8 pf1 = *(const bf16x8*)(Pw + l16 * STR + 32 + quad * 8);
        for (int nt = 0; nt < 4; nt++) {
            bf16x8 vf0 = *(const bf16x8*)(Vts + (nt * 16 + l16) * STR + quad * 8);
            bf16x8 vf1 = *(const bf16x8*)(Vts + (nt * 16 + l16) * STR + 32 + quad * 8);
            acc_o[nt] = mfma16(pf0, vf0, acc_o[nt]);
            acc_o[nt] = mfma16(pf1, vf1, acc_o[nt]);
        }
        __syncthreads();   // protect Ks/Vts before next tile load
    }

    for (int r = 0; r < 4; r++) {
        float inv = 1.f / l_i[r];
        int s = rowg0 + r;
        for (int nt = 0; nt < 4; nt++)
            O[((size_t)b * Sn + s) * Dn + h * DKn + nt * 16 + l16] = f2b(acc_o[nt][r] * inv);
    }
}

// ---------- LayerNorm: one block per row, D=1024, 256 threads x float4 ----------
template <int OUT_BF16>
__global__ __launch_bounds__(256) void ln_kernel(const float* __restrict__ in,
                                                 const float* __restrict__ gamma,
                                                 const float* __restrict__ beta,
                                                 float* __restrict__ outF,
                                                 u16* __restrict__ outB) {
    int row = blockIdx.x, tid = threadIdx.x;
    float4 v = ((const float4*)(in + (size_t)row * Dn))[tid];
    float s = v.x + v.y + v.z + v.w;
    float q = v.x * v.x + v.y * v.y + v.z * v.z + v.w * v.w;
    for (int off = 32; off >= 1; off >>= 1) {
        s += __shfl_xor(s, off, 64);
        q += __shfl_xor(q, off, 64);
    }
    __shared__ float rs[4], rq[4];
    int wave = tid >> 6, lane = tid & 63;
    if (lane == 0) { rs[wave] = s; rq[wave] = q; }
    __syncthreads();
    s = rs[0] + rs[1] + rs[2] + rs[3];
    q = rq[0] + rq[1] + rq[2] + rq[3];
    float mu = s * (1.f / Dn);
    float rstd = rsqrtf(q * (1.f / Dn) - mu * mu + 1e-5f);
    float4 g = ((const float4*)gamma)[tid];
    float4 be = ((const float4*)beta)[tid];
    float o0 = (v.x - mu) * rstd * g.x + be.x;
    float o1 = (v.y - mu) * rstd * g.y + be.y;
    float o2 = (v.z - mu) * rstd * g.z + be.z;
    float o3 = (v.w - mu) * rstd * g.w + be.w;
    if (OUT_BF16) {
        ushort4 u;
        u.x = f2b(o0); u.y = f2b(o1); u.z = f2b(o2); u.w = f2b(o3);
        ((ushort4*)outB)[(size_t)row * (Dn / 4) + tid] = u;
    } else {
        ((float4*)outF)[(size_t)row * (Dn / 4) + tid] = make_float4(o0, o1, o2, o3);
    }
}

extern "C" void kernel_launch(void* const* d_in, const int* in_sizes, int n_in,
                              void* d_out, int out_size, void* d_ws, size_t ws_size,
                              hipStream_t stream) {
    const float* x  = (const float*)d_in[0];
    // d_in[1]: mask (always tril — causal handled analytically)
    const float* Wq = (const float*)d_in[2];  const float* bq = (const float*)d_in[3];
    const float* Wk = (const float*)d_in[4];  const float* bk = (const float*)d_in[5];
    const float* Wv = (const float*)d_in[6];  const float* bv = (const float*)d_in[7];
    const float* Wo = (const float*)d_in[8];  const float* bo = (const float*)d_in[9];
    const float* g1 = (const float*)d_in[10]; const float* b1 = (const float*)d_in[11];
    const float* W1 = (const float*)d_in[12]; const float* c1 = (const float*)d_in[13];
    const float* W2 = (const float*)d_in[14]; const float* c2 = (const float*)d_in[15];
    const float* g2 = (const float*)d_in[16]; const float* b2 = (const float*)d_in[17];

    char* ws = (char*)d_ws;
    const size_t MB = 1ull << 20;
    u16*   Xb  = (u16*)(ws + 0 * MB);     // 16 MB  x bf16
    u16*   WqT = (u16*)(ws + 16 * MB);    // 2 MB
    u16*   WkT = (u16*)(ws + 18 * MB);    // 2 MB
    u16*   WvT = (u16*)(ws + 20 * MB);    // 2 MB
    u16*   WoT = (u16*)(ws + 22 * MB);    // 2 MB
    u16*   W1T = (u16*)(ws + 24 * MB);    // 8 MB
    u16*   W2T = (u16*)(ws + 32 * MB);    // 8 MB
    u16*   Qb  = (u16*)(ws + 40 * MB);    // 16 MB (B*H,S,DK); reused as ln1 bf16
    u16*   Kb  = (u16*)(ws + 56 * MB);    // 16 MB
    u16*   Vb  = (u16*)(ws + 72 * MB);    // 16 MB
    u16*   Ob  = (u16*)(ws + 88 * MB);    // 16 MB (B,S,D)
    float* h1  = (float*)(ws + 104 * MB); // 32 MB x + attn@Wo; reused as h2
    u16*   ff1 = (u16*)(ws + 136 * MB);   // 64 MB relu(ln1@W1+c1)   [total 200 MB]
    u16*   ln1b = Qb;
    float* h2   = h1;

    dim3 tb(32, 8);
    cvt_f32_bf16<<<dim3(Mn * Dn / (256 * 8)), 256, 0, stream>>>(x, Xb);
    transpose_cvt<<<dim3(Dn / 32, Dn / 32), tb, 0, stream>>>(Wq, WqT, Dn, Dn);
    transpose_cvt<<<dim3(Dn / 32, Dn / 32), tb, 0, stream>>>(Wk, WkT, Dn, Dn);
    transpose_cvt<<<dim3(Dn / 32, Dn / 32), tb, 0, stream>>>(Wv, WvT, Dn, Dn);
    transpose_cvt<<<dim3(Dn / 32, Dn / 32), tb, 0, stream>>>(Wo, WoT, Dn, Dn);
    transpose_cvt<<<dim3(Fn / 32, Dn / 32), tb, 0, stream>>>(W1, W1T, Dn, Fn);
    transpose_cvt<<<dim3(Dn / 32, Fn / 32), tb, 0, stream>>>(W2, W2T, Fn, Dn);

    gemm_kernel<0, 0, 1, 1><<<dim3(Mn / 128, Dn / 128), 256, 0, stream>>>(
        Xb, WqT, bq, nullptr, nullptr, nullptr, Qb, Mn, Dn, Dn);
    gemm_kernel<0, 0, 1, 1><<<dim3(Mn / 128, Dn / 128), 256, 0, stream>>>(
        Xb, WkT, bk, nullptr, nullptr, nullptr, Kb, Mn, Dn, Dn);
    gemm_kernel<0, 0, 1, 1><<<dim3(Mn / 128, Dn / 128), 256, 0, stream>>>(
        Xb, WvT, bv, nullptr, nullptr, nullptr, Vb, Mn, Dn, Dn);

    attn_kernel<<<dim3(Sn / 64, Bn * Hn), 256, 0, stream>>>(Qb, Kb, Vb, Ob);

    gemm_kernel<0, 1, 0, 0><<<dim3(Mn / 128, Dn / 128), 256, 0, stream>>>(
        Ob, WoT, bo, x, nullptr, h1, nullptr, Mn, Dn, Dn);
    ln_kernel<1><<<Mn, 256, 0, stream>>>(h1, g1, b1, nullptr, ln1b);

    gemm_kernel<1, 0, 1, 0><<<dim3(Mn / 128, Fn / 128), 256, 0, stream>>>(
        ln1b, W1T, c1, nullptr, nullptr, nullptr, ff1, Mn, Fn, Dn);
    gemm_kernel<0, 2, 0, 0><<<dim3(Mn / 128, Dn / 128), 256, 0, stream>>>(
        ff1, W2T, c2, nullptr, ln1b, h2, nullptr, Mn, Dn, Fn);
    ln_kernel<0><<<Mn, 256, 0, stream>>>(h2, g2, b2, (float*)d_out, nullptr);
}